// Round 1
// baseline (220.670 us; speedup 1.0000x reference)
//
#include <hip/hip_runtime.h>
#include <hip/hip_bf16.h>

// Fused ColorSobelLoss: u8 -> gray -> sobel(k=1) -> threshold -> gauss3x3 -> masked edges,
// for y_pred and y_true, reduced to (loss_sobel, loss_color_edge).
// One tiled kernel, 32x32 outputs per 256-thread block, LDS staging with halo 2.

constexpr int Bn = 16, Hn = 512, Wn = 512;
constexpr int TILE = 32;
constexpr int GDIM = TILE + 4;   // gray tile with halo 2 -> 36
constexpr int SDIM = TILE + 2;   // sobel tile with halo 1 -> 34

__device__ __forceinline__ float u8f(float v) {
    return floorf(fminf(fmaxf(v * 255.0f, 0.0f), 255.0f));
}

__device__ __forceinline__ int reflect101(int i, int n) {
    // halo <= 2, n >= 3, so one fold suffices
    if (i < 0) return -i;
    if (i >= n) return 2 * n - 2 - i;
    return i;
}

__global__ void zero_out_kernel(float* out) {
    out[0] = 0.0f;
    out[1] = 0.0f;
}

__global__ __launch_bounds__(256)
void color_sobel_loss_kernel(const float* __restrict__ pred,
                             const float* __restrict__ tru,
                             float* __restrict__ out) {
    const int b   = blockIdx.z;
    const int ty0 = blockIdx.y * TILE;
    const int tx0 = blockIdx.x * TILE;
    const int tid = threadIdx.x;

    __shared__ float gp[GDIM][GDIM + 1];
    __shared__ float gt[GDIM][GDIM + 1];
    __shared__ float sp[SDIM][SDIM + 1];
    __shared__ float st[SDIM][SDIM + 1];

    const size_t img_base = (size_t)b * 3 * Hn * Wn;
    const size_t chs = (size_t)Hn * Wn;

    // ---- Stage 1: gray tiles (36x36) with reflect-101 halo ----
    for (int idx = tid; idx < GDIM * GDIM; idx += 256) {
        const int ly = idx / GDIM;
        const int lx = idx - ly * GDIM;
        const int gy = reflect101(ty0 + ly - 2, Hn);
        const int gx = reflect101(tx0 + lx - 2, Wn);
        const size_t base = img_base + (size_t)gy * Wn + gx;

        float r = u8f(pred[base]);
        float g = u8f(pred[base + chs]);
        float bl = u8f(pred[base + 2 * chs]);
        gp[ly][lx] = rintf((0.299f * r + 0.587f * g) + 0.114f * bl);

        r = u8f(tru[base]);
        g = u8f(tru[base + chs]);
        bl = u8f(tru[base + 2 * chs]);
        gt[ly][lx] = rintf((0.299f * r + 0.587f * g) + 0.114f * bl);
    }
    __syncthreads();

    // ---- Stage 2: sobelxy tiles (34x34) ----
    for (int idx = tid; idx < SDIM * SDIM; idx += 256) {
        const int ly = idx / SDIM;
        const int lx = idx - ly * SDIM;

        float sx = fminf(fabsf(gp[ly + 1][lx + 2] - gp[ly + 1][lx]), 255.0f);
        float sy = fminf(fabsf(gp[ly + 2][lx + 1] - gp[ly][lx + 1]), 255.0f);
        sp[ly][lx] = rintf(0.5f * sx + 0.5f * sy);

        sx = fminf(fabsf(gt[ly + 1][lx + 2] - gt[ly + 1][lx]), 255.0f);
        sy = fminf(fabsf(gt[ly + 2][lx + 1] - gt[ly][lx + 1]), 255.0f);
        st[ly][lx] = rintf(0.5f * sx + 0.5f * sy);
    }
    __syncthreads();

    // ---- Stage 3: blur, keep-mask, per-thread loss accumulation (4 px/thread) ----
    float acc_s = 0.0f;  // sum |p_sobel - t_sobel|
    float acc_e = 0.0f;  // sum |p_edge - t_edge| over 3 channels

    for (int j = 0; j < 4; ++j) {
        const int p  = tid + j * 256;
        const int ly = p >> 5;
        const int lx = p & 31;

        acc_s += fabsf(sp[ly + 1][lx + 1] - st[ly + 1][lx + 1]);

        float vbp = 0.0f, vbt = 0.0f;
        const float wv[3] = {0.25f, 0.5f, 0.25f};
        #pragma unroll
        for (int d = 0; d < 3; ++d) {
            float m0 = sp[ly + d][lx]     > 10.0f ? 255.0f : 0.0f;
            float m1 = sp[ly + d][lx + 1] > 10.0f ? 255.0f : 0.0f;
            float m2 = sp[ly + d][lx + 2] > 10.0f ? 255.0f : 0.0f;
            vbp += wv[d] * ((0.25f * m0 + 0.5f * m1) + 0.25f * m2);

            m0 = st[ly + d][lx]     > 10.0f ? 255.0f : 0.0f;
            m1 = st[ly + d][lx + 1] > 10.0f ? 255.0f : 0.0f;
            m2 = st[ly + d][lx + 2] > 10.0f ? 255.0f : 0.0f;
            vbt += wv[d] * ((0.25f * m0 + 0.5f * m1) + 0.25f * m2);
        }
        const float keep_p = rintf(vbp) > 0.0f ? 1.0f : 0.0f;
        const float keep_t = rintf(vbt) > 0.0f ? 1.0f : 0.0f;

        const int gy = ty0 + ly;
        const int gx = tx0 + lx;
        const size_t base = img_base + (size_t)gy * Wn + gx;
        #pragma unroll
        for (int c = 0; c < 3; ++c) {
            const float up = u8f(pred[base + (size_t)c * chs]);
            const float ut = u8f(tru[base + (size_t)c * chs]);
            acc_e += fabsf(up * keep_p - ut * keep_t);
        }
    }

    // ---- Stage 4: block reduction (wave64 shuffle + LDS across 4 waves) ----
    #pragma unroll
    for (int off = 32; off > 0; off >>= 1) {
        acc_s += __shfl_down(acc_s, off, 64);
        acc_e += __shfl_down(acc_e, off, 64);
    }
    __shared__ float wsum_s[4], wsum_e[4];
    const int wave = tid >> 6;
    const int lane = tid & 63;
    if (lane == 0) { wsum_s[wave] = acc_s; wsum_e[wave] = acc_e; }
    __syncthreads();
    if (tid == 0) {
        const float ps = (wsum_s[0] + wsum_s[1]) + (wsum_s[2] + wsum_s[3]);
        const float pe = (wsum_e[0] + wsum_e[1]) + (wsum_e[2] + wsum_e[3]);
        // loss_sobel = sum / (255 * B*H*W); loss_edge = sum / (255 * B*H*W*3)
        const float inv_s = 1.0f / (255.0f * (float)Bn * (float)Hn * (float)Wn);
        const float inv_e = inv_s / 3.0f;
        atomicAdd(&out[0], ps * inv_s);
        atomicAdd(&out[1], pe * inv_e);
    }
}

extern "C" void kernel_launch(void* const* d_in, const int* in_sizes, int n_in,
                              void* d_out, int out_size, void* d_ws, size_t ws_size,
                              hipStream_t stream) {
    const float* pred = (const float*)d_in[0];
    const float* tru  = (const float*)d_in[1];
    float* out = (float*)d_out;

    zero_out_kernel<<<1, 1, 0, stream>>>(out);

    dim3 grid(Wn / TILE, Hn / TILE, Bn);  // 16 x 16 x 16 = 4096 blocks
    color_sobel_loss_kernel<<<grid, 256, 0, stream>>>(pred, tru, out);
}

// Round 2
// 158.008 us; speedup vs baseline: 1.3966x; 1.3966x over previous
//
#include <hip/hip_runtime.h>

// Fused ColorSobelLoss, round 2: vectorized float4 pipeline, no stage-3 global
// re-read (D/Su/St cached in registers), combined pred+true mask through the
// Gaussian blur (exact: blur = (255/16)*(m + 1024*n), fits f32 mantissa).
// Tile 128x16 per 256-thread block.

constexpr int Bn = 16, Hn = 512, Wn = 512;
constexpr int TX = 128, TY = 16;
constexpr int GROWS = TY + 4;   // 20 gray rows (halo 2)
constexpr int GCOLS = 140;      // cols 2..133 used (center 4..131); 560B row = 16B-aligned
constexpr int MROWS = TY + 2;   // 18 mask rows (halo 1)
constexpr int MCOLS = 140;      // mask col = (x - tx0) + 4; used 3..132

__device__ __forceinline__ float u8q(float v) {
    return floorf(fminf(fmaxf(v * 255.0f, 0.0f), 255.0f));
}
__device__ __forceinline__ int reflect101(int i, int n) {
    if (i < 0) return -i;
    if (i >= n) return 2 * n - 2 - i;
    return i;
}
__device__ __forceinline__ float gray1(float r, float g, float b) {
    return rintf((0.299f * r + 0.587f * g) + 0.114f * b);
}
__device__ __forceinline__ float4 u8q4(float4 v) {
    return make_float4(u8q(v.x), u8q(v.y), u8q(v.z), u8q(v.w));
}
__device__ __forceinline__ float4 gray4(float4 r, float4 g, float4 b) {
    return make_float4(gray1(r.x, g.x, b.x), gray1(r.y, g.y, b.y),
                       gray1(r.z, g.z, b.z), gray1(r.w, g.w, b.w));
}

__global__ void zero_out_kernel(float* out) { out[0] = 0.0f; out[1] = 0.0f; }

__global__ __launch_bounds__(256)
void csl_kernel(const float* __restrict__ pred, const float* __restrict__ tru,
                float* __restrict__ out) {
    const int b   = blockIdx.z;
    const int ty0 = blockIdx.y * TY;
    const int tx0 = blockIdx.x * TX;
    const int tid = threadIdx.x;

    __shared__ float gp[GROWS][GCOLS];
    __shared__ float gt[GROWS][GCOLS];
    __shared__ float mc[MROWS][MCOLS];

    const size_t chs = (size_t)Hn * Wn;
    const size_t img_base = (size_t)b * 3 * chs;
    const float* pb = pred + img_base;
    const float* tb = tru + img_base;

    float4 Dv[2], Suv[2], Stv[2];  // per-pixel edge-term precomputes, 4 px per slot

    // ---- Stage 1a: center rows (16 x 128), vec4, keep D/Su/St in regs ----
    #pragma unroll
    for (int j = 0; j < 2; ++j) {
        const int pos = tid + 256 * j;
        const int r = 2 + (pos >> 5);      // gray row 2..17
        const int q = pos & 31;
        const int gy = ty0 + r - 2;        // in-image, no reflect
        const size_t off = (size_t)gy * Wn + tx0 + 4 * q;

        float4 R  = u8q4(*(const float4*)(pb + off));
        float4 G  = u8q4(*(const float4*)(pb + chs + off));
        float4 Bc = u8q4(*(const float4*)(pb + 2 * chs + off));
        float4 Rt = u8q4(*(const float4*)(tb + off));
        float4 Gt = u8q4(*(const float4*)(tb + chs + off));
        float4 Bt = u8q4(*(const float4*)(tb + 2 * chs + off));

        *(float4*)&gp[r][4 + 4 * q] = gray4(R, G, Bc);
        *(float4*)&gt[r][4 + 4 * q] = gray4(Rt, Gt, Bt);

        Suv[j] = make_float4(R.x + G.x + Bc.x, R.y + G.y + Bc.y,
                             R.z + G.z + Bc.z, R.w + G.w + Bc.w);
        Stv[j] = make_float4(Rt.x + Gt.x + Bt.x, Rt.y + Gt.y + Bt.y,
                             Rt.z + Gt.z + Bt.z, Rt.w + Gt.w + Bt.w);
        Dv[j] = make_float4(
            fabsf(R.x - Rt.x) + fabsf(G.x - Gt.x) + fabsf(Bc.x - Bt.x),
            fabsf(R.y - Rt.y) + fabsf(G.y - Gt.y) + fabsf(Bc.y - Bt.y),
            fabsf(R.z - Rt.z) + fabsf(G.z - Gt.z) + fabsf(Bc.z - Bt.z),
            fabsf(R.w - Rt.w) + fabsf(G.w - Gt.w) + fabsf(Bc.w - Bt.w));
    }

    // ---- Stage 1b: halo rows (0,1,18,19), vec4, gray only ----
    if (tid < 128) {
        const int rh = tid >> 5;
        const int q = tid & 31;
        const int r = (rh < 2) ? rh : rh + 16;  // 0,1,18,19
        const int gy = reflect101(ty0 + r - 2, Hn);
        const size_t off = (size_t)gy * Wn + tx0 + 4 * q;
        float4 R  = u8q4(*(const float4*)(pb + off));
        float4 G  = u8q4(*(const float4*)(pb + chs + off));
        float4 Bc = u8q4(*(const float4*)(pb + 2 * chs + off));
        *(float4*)&gp[r][4 + 4 * q] = gray4(R, G, Bc);
        float4 Rt = u8q4(*(const float4*)(tb + off));
        float4 Gt = u8q4(*(const float4*)(tb + chs + off));
        float4 Bt = u8q4(*(const float4*)(tb + 2 * chs + off));
        *(float4*)&gt[r][4 + 4 * q] = gray4(Rt, Gt, Bt);
    }

    // ---- Stage 1c: halo cols (x = tx0-2,-1,+128,+129), scalar ----
    if (tid < 80) {
        const int r = tid >> 2;          // 0..19
        const int c = tid & 3;
        const int gy = reflect101(ty0 + r - 2, Hn);
        int gx = tx0 + ((c < 2) ? (c - 2) : (c + 126));  // -2,-1,128,129
        gx = reflect101(gx, Wn);
        const int lc = (c < 2) ? (c + 2) : (c + 130);    // 2,3,132,133
        const size_t off = (size_t)gy * Wn + gx;
        gp[r][lc] = gray1(u8q(pb[off]), u8q(pb[off + chs]), u8q(pb[off + 2 * chs]));
        gt[r][lc] = gray1(u8q(tb[off]), u8q(tb[off + chs]), u8q(tb[off + 2 * chs]));
    }
    __syncthreads();

    // ---- Stage 2: sobel both imgs, fused |sp-st| loss, combined mask ----
    float acc_s = 0.0f;

    auto sobel_vec = [&](int r, int q, bool center) {
        const int cb = 4 + 4 * q;
        float4 upP = *(const float4*)&gp[r][cb];
        float4 dnP = *(const float4*)&gp[r + 2][cb];
        float4 mdP = *(const float4*)&gp[r + 1][cb];
        float2 lfP = *(const float2*)&gp[r + 1][cb - 2];
        float2 rtP = *(const float2*)&gp[r + 1][cb + 4];
        float4 upT = *(const float4*)&gt[r][cb];
        float4 dnT = *(const float4*)&gt[r + 2][cb];
        float4 mdT = *(const float4*)&gt[r + 1][cb];
        float2 lfT = *(const float2*)&gt[r + 1][cb - 2];
        float2 rtT = *(const float2*)&gt[r + 1][cb + 4];

        float sxp[4] = {mdP.y - lfP.y, mdP.z - mdP.x, mdP.w - mdP.y, rtP.x - mdP.z};
        float syp[4] = {dnP.x - upP.x, dnP.y - upP.y, dnP.z - upP.z, dnP.w - upP.w};
        float sxt[4] = {mdT.y - lfT.y, mdT.z - mdT.x, mdT.w - mdT.y, rtT.x - mdT.z};
        float syt[4] = {dnT.x - upT.x, dnT.y - upT.y, dnT.z - upT.z, dnT.w - upT.w};

        float4 m;
        float* mp = &m.x;
        #pragma unroll
        for (int i = 0; i < 4; ++i) {
            float sp = rintf(0.5f * fminf(fabsf(sxp[i]), 255.0f) +
                             0.5f * fminf(fabsf(syp[i]), 255.0f));
            float st = rintf(0.5f * fminf(fabsf(sxt[i]), 255.0f) +
                             0.5f * fminf(fabsf(syt[i]), 255.0f));
            if (center) acc_s += fabsf(sp - st);
            mp[i] = (sp > 10.0f ? 255.0f : 0.0f) + (st > 10.0f ? 261120.0f : 0.0f);
        }
        *(float4*)&mc[r][cb] = m;
    };

    {
        const int r = tid >> 5, q = tid & 31;       // r 0..7
        sobel_vec(r, q, r >= 1);
    }
    {
        const int pos = tid + 256;
        sobel_vec(pos >> 5, pos & 31, true);        // r 8..15 all center
    }
    if (tid < 64) {
        const int pos = tid + 512;
        const int r = pos >> 5;                      // 16,17
        sobel_vec(r, pos & 31, r < 17);
    }
    if (tid < 36) {  // edge cols x = tx0-1 (col 3), x = tx0+128 (col 132)
        const int r = tid >> 1, c = tid & 1;
        const int gc = c ? 132 : 3;
        float sxp = gp[r + 1][gc + 1] - gp[r + 1][gc - 1];
        float syp = gp[r + 2][gc] - gp[r][gc];
        float sxt = gt[r + 1][gc + 1] - gt[r + 1][gc - 1];
        float syt = gt[r + 2][gc] - gt[r][gc];
        float sp = rintf(0.5f * fminf(fabsf(sxp), 255.0f) +
                         0.5f * fminf(fabsf(syp), 255.0f));
        float st = rintf(0.5f * fminf(fabsf(sxt), 255.0f) +
                         0.5f * fminf(fabsf(syt), 255.0f));
        mc[r][gc] = (sp > 10.0f ? 255.0f : 0.0f) + (st > 10.0f ? 261120.0f : 0.0f);
    }
    __syncthreads();

    // ---- Stage 3: blur combined mask, decode keep flags, edge loss ----
    float acc_e = 0.0f;
    #pragma unroll
    for (int j = 0; j < 2; ++j) {
        const int pos = tid + 256 * j;
        const int py = pos >> 5;   // 0..15 (matches stage-1a slot j)
        const int q = pos & 31;
        const int cb = 4 * q;

        float4 M0 = *(const float4*)&mc[py][cb + 4];
        float  l0 = mc[py][cb + 3],     r0 = mc[py][cb + 8];
        float4 M1 = *(const float4*)&mc[py + 1][cb + 4];
        float  l1 = mc[py + 1][cb + 3], r1 = mc[py + 1][cb + 8];
        float4 M2 = *(const float4*)&mc[py + 2][cb + 4];
        float  l2 = mc[py + 2][cb + 3], r2 = mc[py + 2][cb + 8];

        float vm[6];
        vm[0] = 0.25f * (l0 + l2) + 0.5f * l1;
        vm[1] = 0.25f * (M0.x + M2.x) + 0.5f * M1.x;
        vm[2] = 0.25f * (M0.y + M2.y) + 0.5f * M1.y;
        vm[3] = 0.25f * (M0.z + M2.z) + 0.5f * M1.z;
        vm[4] = 0.25f * (M0.w + M2.w) + 0.5f * M1.w;
        vm[5] = 0.25f * (r0 + r2) + 0.5f * r1;

        const float Da[4]  = {Dv[j].x, Dv[j].y, Dv[j].z, Dv[j].w};
        const float Sua[4] = {Suv[j].x, Suv[j].y, Suv[j].z, Suv[j].w};
        const float Sta[4] = {Stv[j].x, Stv[j].y, Stv[j].z, Stv[j].w};
        const float dec = 16.0f / 255.0f;
        #pragma unroll
        for (int i = 0; i < 4; ++i) {
            float v = 0.25f * (vm[i] + vm[i + 2]) + 0.5f * vm[i + 1];
            int t = (int)rintf(v * dec);     // t = m + 1024*n exactly
            int mpx = t & 1023;              // pred blur numerator (16ths)
            int npx = t >> 10;               // true blur numerator
            float a  = (npx > 0) ? Da[i]  : Sua[i];
            float bs = (npx > 0) ? Sta[i] : 0.0f;
            acc_e += (mpx > 0) ? a : bs;
        }
    }

    // ---- Block reduction ----
    #pragma unroll
    for (int off = 32; off > 0; off >>= 1) {
        acc_s += __shfl_down(acc_s, off, 64);
        acc_e += __shfl_down(acc_e, off, 64);
    }
    __shared__ float wsum[8];
    const int wave = tid >> 6, lane = tid & 63;
    if (lane == 0) { wsum[wave] = acc_s; wsum[wave + 4] = acc_e; }
    __syncthreads();
    if (tid == 0) {
        const float ps = (wsum[0] + wsum[1]) + (wsum[2] + wsum[3]);
        const float pe = (wsum[4] + wsum[5]) + (wsum[6] + wsum[7]);
        const float inv_s = 1.0f / (255.0f * (float)Bn * (float)Hn * (float)Wn);
        atomicAdd(&out[0], ps * inv_s);
        atomicAdd(&out[1], pe * (inv_s / 3.0f));
    }
}

extern "C" void kernel_launch(void* const* d_in, const int* in_sizes, int n_in,
                              void* d_out, int out_size, void* d_ws, size_t ws_size,
                              hipStream_t stream) {
    const float* pred = (const float*)d_in[0];
    const float* tru  = (const float*)d_in[1];
    float* out = (float*)d_out;

    zero_out_kernel<<<1, 1, 0, stream>>>(out);

    dim3 grid(Wn / TX, Hn / TY, Bn);  // 4 x 32 x 16 = 2048 blocks
    csl_kernel<<<grid, 256, 0, stream>>>(pred, tru, out);
}